// Round 15
// baseline (88.960 us; speedup 1.0000x reference)
//
#include <hip/hip_runtime.h>
#include <hip/hip_bf16.h>

// GMM log-likelihood, N=65536, K=32, F=128.
// Direct-stream design: NO LDS staging of P at all. Wave (gh,nq) owns 64 g x
// 64 n; per comp it streams its 16 P-fragments global->VGPR in two 8-frag
// banks, interleaved AITER-style with the MFMA clusters (issue bank B ->
// 16 MFMAs from bank A -> issue next comp's bank A -> 16 MFMAs from bank B).
// Compiler emits counted vmcnt at use (~vmcnt(8)); each bank has a full
// half-comp (~500 cyc) to cover L1/L2 latency. Aimg slab (32 KB) is L1/L2
// resident (1 MB total, shared by all waves). The only per-comp sync is a
// raw s_barrier + lgkmcnt(0) for the 1-float pairwise xch exchange -- no
// vmcnt drain, no staging publication, no convoy.
// v-trick mean fold (xv in LDS table); zc C-operand; LSE inline per comp.
// Registers ~233/256 at 2 waves/SIMD: xf[2][8]=64, frA+frB=64, acc 64 AGPR,
// zc 16 AGPR, temps ~25.

#define NPTS 65536
#define KC 32
#define FD 128
#define SLABB 32768  // 4 q * 8 s * 64 lanes * 16 B per component

typedef __attribute__((ext_vector_type(8))) short short8;
typedef __attribute__((ext_vector_type(8))) unsigned short ushort8;
typedef __attribute__((ext_vector_type(16))) float f32x16;

#define MFMA(A, B, C) __builtin_amdgcn_mfma_f32_32x32x16_bf16((A), (B), (C), 0, 0, 0)

static __device__ __forceinline__ unsigned short f2bf(float f) {
  unsigned int u = __float_as_uint(f);
  u += 0x7FFFu + ((u >> 16) & 1u);  // RNE
  return (unsigned short)(u >> 16);
}

// --- prep12: fused. smp[g] = mu_k @ P_k[:,g]; v[k][f] = P_k[f,:] @ smp;
//     ck3[k] = log w + logdet - 0.5*(F*log2pi + sum_g smp^2) ---
__global__ void prep12(const float* __restrict__ means, const float* __restrict__ P,
                       const float* __restrict__ w, float* __restrict__ v,
                       float* __restrict__ ck3) {
  int k = blockIdx.x, g = threadIdx.x;  // 32 x 128
  const float* Pk = P + k * FD * FD;
  float acc = 0.f;
  for (int f = 0; f < FD; ++f) acc = fmaf(means[k * FD + f], Pk[f * FD + g], acc);
  __shared__ float smp[FD], r1[FD], r2[FD];
  smp[g] = acc;
  r1[g] = logf(Pk[g * FD + g]);
  r2[g] = acc * acc;
  __syncthreads();
  const float* Pr = Pk + g * FD;
  float a2 = 0.f;
  for (int j = 0; j < FD; ++j) a2 = fmaf(Pr[j], smp[j], a2);
  v[k * FD + g] = a2;
  for (int off = 64; off; off >>= 1) {
    if (g < off) { r1[g] += r1[g + off]; r2[g] += r2[g + off]; }
    __syncthreads();
  }
  if (g == 0)
    ck3[k] = logf(w[k]) + r1[0] - 0.5f * ((float)FD * 1.8378770664093453f + r2[0]);
}

// --- prep3: xv mini-slab (8 KB): A'[row k][f] = v[k][f], frag-major ---
__global__ void prep3(const float* __restrict__ v, unsigned char* __restrict__ Ximg) {
  int id = blockIdx.x * 256 + threadIdx.x;  // 0..511 chunks
  int l = id & 63, s = id >> 6;
  int r = l & 31, f0 = 16 * s + 8 * (l >> 5);
  ushort8 o;
#pragma unroll
  for (int j = 0; j < 8; ++j) o[j] = f2bf(v[r * FD + f0 + j]);
  *(ushort8*)(Ximg + (size_t)id * 16) = o;
}

// --- prep4: frag-major bf16 A image. chunk id -> (k,q,s,lane). ---
__global__ void prep4(const float* __restrict__ P, unsigned char* __restrict__ Aimg) {
  int id = blockIdx.x * 256 + threadIdx.x;  // 0..65535
  int l = id & 63;
  int s = (id >> 6) & 7;
  int q = (id >> 9) & 3;
  int k = id >> 11;
  int g = q * 32 + (l & 31);
  int f0 = 16 * s + 8 * (l >> 5);
  ushort8 o;
#pragma unroll
  for (int j = 0; j < 8; ++j) o[j] = f2bf(P[k * 16384 + (f0 + j) * 128 + g]);
  *(ushort8*)(Aimg + (size_t)id * 16) = o;
}

// --- main ---
__global__ __launch_bounds__(512, 2) void gmm_main(const float* __restrict__ x,
                                                   const unsigned char* __restrict__ Aimg,
                                                   const unsigned char* __restrict__ Ximg,
                                                   const float* __restrict__ ck3,
                                                   float* __restrict__ out) {
  __shared__ __align__(16) float xvt[8][KC][32];  // 32 KB xv table
  __shared__ __align__(16) float xch[2][8][32];   // parity-dbuf pairwise exchange
  __shared__ float ck[KC];
  const int tid = threadIdx.x;
  const int wid = tid >> 6;   // 0..7
  const int lane = tid & 63;
  const int half = lane >> 5;
  const int ln = lane & 31;
  const int gh = wid & 1;     // g-half this wave owns (g-tiles gh*2, gh*2+1)
  const int nq = wid >> 1;    // n-quarter this wave owns (64 x-rows)
  const int nbase = blockIdx.x * 256;

  if (tid < KC) ck[tid] = ck3[tid];

  // B fragments: this wave's 64 x-rows (2 n-tiles), resident all kernel.
  // xf[t][s][j] = x[nbase + nq*64 + t*32 + ln][16s + 8*half + j]  (64 VGPR)
  short8 xf[2][8];
#pragma unroll
  for (int t = 0; t < 2; ++t) {
    const float* xr = x + (size_t)(nbase + nq * 64 + t * 32 + ln) * FD + 8 * half;
#pragma unroll
    for (int s = 0; s < 8; ++s) {
      const float4 a = *(const float4*)(xr + 16 * s);
      const float4 b = *(const float4*)(xr + 16 * s + 4);
      short8 f;
      f[0] = (short)f2bf(a.x); f[1] = (short)f2bf(a.y);
      f[2] = (short)f2bf(a.z); f[3] = (short)f2bf(a.w);
      f[4] = (short)f2bf(b.x); f[5] = (short)f2bf(b.y);
      f[6] = (short)f2bf(b.z); f[7] = (short)f2bf(b.w);
      xf[t][s] = f;
    }
  }

  f32x16 zc;  // persistent zero C-operand
#pragma unroll
  for (int i = 0; i < 16; ++i) zc[i] = 0.f;

  // xv mini-GEMM for the n-tile this wave finalizes (t == gh), fragments
  // streamed straight from global (Ximg is 8 KB, L1/L2-hit for all waves).
  // result row k = (i&3)+8*(i>>2)+4*half, col n = nbase + nq*64 + gh*32 + ln
  {
    const unsigned char* xb = Ximg + lane * 16;
    f32x16 xv;
    {
      const short8 fx = *(const short8*)xb;
      xv = MFMA(fx, xf[gh][0], zc);
    }
#pragma unroll
    for (int s = 1; s < 8; ++s) {
      const short8 fx = *(const short8*)(xb + s * 1024);
      xv = MFMA(fx, xf[gh][s], xv);
    }
#pragma unroll
    for (int i = 0; i < 16; ++i) {
      const int kk = (i & 3) + 8 * (i >> 2) + 4 * half;
      xvt[wid][kk][ln] = xv[i];
    }
  }
  __syncthreads();  // prologue only: xvt published

  float m = -__builtin_inff(), ssum = 0.f;

  // P-fragment stream, two 8-frag banks, wave-private.
  const unsigned char* Abase = Aimg + gh * 16384 + lane * 16;
  short8 frA[8], frB[8];
#pragma unroll
  for (int s = 0; s < 8; ++s) frA[s] = *(const short8*)(Abase + s * 1024);  // (0, g2=0)

  for (int k = 0; k < KC; ++k) {
    const unsigned char* Ak = Abase + (size_t)k * SLABB;
    // issue (k, g2=1) -> frB (used after ~16 MFMAs; latency covered)
#pragma unroll
    for (int s = 0; s < 8; ++s) frB[s] = *(const short8*)(Ak + 8192 + s * 1024);
    __builtin_amdgcn_s_setprio(1);
    f32x16 aA0 = MFMA(frA[0], xf[0][0], zc);
    f32x16 aA1 = MFMA(frA[0], xf[1][0], zc);
#pragma unroll
    for (int s = 1; s < 8; ++s) {
      aA0 = MFMA(frA[s], xf[0][s], aA0);
      aA1 = MFMA(frA[s], xf[1][s], aA1);
    }
    __builtin_amdgcn_s_setprio(0);
    // issue (k+1, g2=0) -> frA (bank dead after the cluster above issued)
    if (k + 1 < KC) {
      const unsigned char* An = Ak + SLABB;
#pragma unroll
      for (int s = 0; s < 8; ++s) frA[s] = *(const short8*)(An + s * 1024);
    }
    __builtin_amdgcn_s_setprio(1);
    f32x16 aB0 = MFMA(frB[0], xf[0][0], zc);
    f32x16 aB1 = MFMA(frB[0], xf[1][0], zc);
#pragma unroll
    for (int s = 1; s < 8; ++s) {
      aB0 = MFMA(frB[s], xf[0][s], aB0);
      aB1 = MFMA(frB[s], xf[1][s], aB1);
    }
    __builtin_amdgcn_s_setprio(0);
    // epilogue: per-n-tile squares over this wave's 64 g
    float q0a = 0.f, q0b = 0.f, q1a = 0.f, q1b = 0.f;
#pragma unroll
    for (int i = 0; i < 16; ++i) {
      q0a = fmaf(aA0[i], aA0[i], q0a);
      q0b = fmaf(aB0[i], aB0[i], q0b);
      q1a = fmaf(aA1[i], aA1[i], q1a);
      q1b = fmaf(aB1[i], aB1[i], q1b);
    }
    float q0 = q0a + q0b, q1 = q1a + q1b;
    q0 += __shfl_xor(q0, 32, 64);  // both halves hold full 64-g partials
    q1 += __shfl_xor(q1, 32, 64);
    const int ph = k & 1;
    float sown = gh ? q1 : q0;  // n-tile this wave finalizes (t == gh)
    float soth = gh ? q0 : q1;  // n-tile the partner (wid^1) finalizes
    if (half == 0) xch[ph][wid ^ 1][ln] = soth;
    // pairwise exchange: LDS-only sync -- no vmcnt drain, frag loads stay in flight
    asm volatile("s_waitcnt lgkmcnt(0)" ::: "memory");
    __builtin_amdgcn_s_barrier();
    asm volatile("" ::: "memory");
    float sfull = sown + xch[ph][wid][ln];
    sfull = fmaf(-2.f, xvt[wid][k][ln], sfull);  // v-trick correction
    float vv = ck[k] - 0.5f * sfull;
    float nm = fmaxf(m, vv);
    ssum = ssum * __expf(m - nm) + __expf(vv - nm);
    m = nm;
  }

  if (half == 0) out[nbase + nq * 64 + gh * 32 + ln] = m + logf(ssum);
}

extern "C" void kernel_launch(void* const* d_in, const int* in_sizes, int n_in,
                              void* d_out, int out_size, void* d_ws, size_t ws_size,
                              hipStream_t stream) {
  const float* x = (const float*)d_in[0];
  const float* means = (const float*)d_in[1];
  const float* P = (const float*)d_in[2];
  const float* w = (const float*)d_in[3];
  float* out = (float*)d_out;

  unsigned char* ws = (unsigned char*)d_ws;
  unsigned char* Aimg = ws;                       // 1048576 B
  unsigned char* Ximg = ws + 1048576;             // 8192 B
  float* v = (float*)(ws + 1048576 + 8192);       // 16384 B
  float* ck3 = (float*)(ws + 1048576 + 24576);    // 128 B

  prep12<<<32, 128, 0, stream>>>(means, P, w, v, ck3);
  prep3<<<2, 256, 0, stream>>>(v, Ximg);
  prep4<<<256, 256, 0, stream>>>(P, Aimg);
  gmm_main<<<NPTS / 256, 512, 0, stream>>>(x, Aimg, Ximg, ck3, out);
}